// Round 2
// baseline (671.717 us; speedup 1.0000x reference)
//
#include <hip/hip_runtime.h>

typedef __attribute__((ext_vector_type(8))) _Float16 f16x8;
typedef __attribute__((ext_vector_type(4))) _Float16 f16x4;
typedef __attribute__((ext_vector_type(4))) float f32x4;

// async global->LDS, 16B per lane; LDS dest = wave-uniform base + lane*16
__device__ inline void gl_lds16(const void* g, void* l) {
  __builtin_amdgcn_global_load_lds(
      (const __attribute__((address_space(1))) unsigned int*)g,
      (__attribute__((address_space(3))) unsigned int*)l, 16, 0, 0);
}

// ---------------- zero-init scratch (replaces hipMemsetAsync) ----------------
__global__ __launch_bounds__(256) void zero_k(float* __restrict__ g, float* __restrict__ n) {
  int i = (blockIdx.x << 8) + threadIdx.x;
  if (i < 262144) g[i] = 0.f;
  if (i < 12288) n[i] = 0.f;
}

// ---------------- split/convert kernels ----------------
// x (f32) -> x_hi (f16), x_lo (f16 residual), x_his (= x_hi * 2^-11)
__global__ __launch_bounds__(256) void split_x_k(
    const float* __restrict__ x, _Float16* __restrict__ hi,
    _Float16* __restrict__ lo, _Float16* __restrict__ his) {
  int i = (blockIdx.x << 8) + threadIdx.x;      // one float4 each
  float4 v = ((const float4*)x)[i];
  float fs[4] = {v.x, v.y, v.z, v.w};
  f16x4 h, l, s;
#pragma unroll
  for (int j = 0; j < 4; ++j) {
    _Float16 hh = (_Float16)fs[j];
    float r = fs[j] - (float)hh;
    h[j] = hh;
    l[j] = (_Float16)r;
    s[j] = (_Float16)((float)hh * 4.8828125e-4f);  // *2^-11
  }
  *(f16x4*)&hi[(size_t)i << 2] = h;
  *(f16x4*)&lo[(size_t)i << 2] = l;
  *(f16x4*)&his[(size_t)i << 2] = s;
}

// W_qkv (512x1536 f32) -> transposed Wt_hi (1536x512 f16), Wt_los (= w_lo * 2^11)
__global__ __launch_bounds__(256) void split_wt_k(
    const float* __restrict__ w, _Float16* __restrict__ hi, _Float16* __restrict__ los) {
  int idx = (blockIdx.x << 8) + threadIdx.x;    // idx = n*512 + k
  int n = idx >> 9, k = idx & 511;
  float f = w[(size_t)k * 1536 + n];
  _Float16 h = (_Float16)f;
  float r = f - (float)h;
  hi[idx] = h;
  los[idx] = (_Float16)(r * 2048.0f);           // *2^11
}

// ---------------- split-f16 MFMA GEMM: qkv16 = x @ W_qkv (f16 out) ----------------
// M=32768, N=1536, K_eff=3*512 (segments: hi*hi, lo*hi, his*los)
__global__ __launch_bounds__(256) void gemm_qkv_k(
    const _Float16* __restrict__ xhi, const _Float16* __restrict__ xlo,
    const _Float16* __restrict__ xhis, const _Float16* __restrict__ whi,
    const _Float16* __restrict__ wlos, _Float16* __restrict__ qkv) {
  __shared__ _Float16 As[128 * 32];   // [m][k], 64B rows
  __shared__ _Float16 Bs[128 * 32];   // [n][k]
  const int tid = threadIdx.x;
  const int wave = tid >> 6, lane = tid & 63;
  const int bn = blockIdx.x;          // 0..11
  const int bm = blockIdx.y;          // 0..255
  const int wm = (wave >> 1) << 6, wn = (wave & 1) << 6;
  const int lhi = lane >> 4, llo = lane & 15;

  f32x4 zero = {};
  f32x4 acc[4][4];
#pragma unroll
  for (int i = 0; i < 4; ++i)
#pragma unroll
    for (int j = 0; j < 4; ++j) acc[i][j] = zero;

  const int arow = (bm << 7) + (wave << 5) + (lane >> 2);
  const int brow = (bn << 7) + (wave << 5) + (lane >> 2);
  const int kc = (lane & 3) << 3;
  _Float16* As0 = &As[(wave << 5) << 5];
  _Float16* As1 = &As[((wave << 5) + 16) << 5];
  _Float16* Bs0 = &Bs[(wave << 5) << 5];
  _Float16* Bs1 = &Bs[((wave << 5) + 16) << 5];

  for (int seg = 0; seg < 3; ++seg) {
    const _Float16* Ag = (seg == 0) ? xhi : ((seg == 1) ? xlo : xhis);
    const _Float16* Bg = (seg == 2) ? wlos : whi;
    const _Float16* a0 = Ag + ((size_t)arow << 9) + kc;
    const _Float16* a1 = Ag + ((size_t)(arow + 16) << 9) + kc;
    const _Float16* b0 = Bg + ((size_t)brow << 9) + kc;
    const _Float16* b1 = Bg + ((size_t)(brow + 16) << 9) + kc;
    for (int ks = 0; ks < 16; ++ks) {
      const int k0 = ks << 5;
      __syncthreads();
      gl_lds16(a0 + k0, As0);
      gl_lds16(a1 + k0, As1);
      gl_lds16(b0 + k0, Bs0);
      gl_lds16(b1 + k0, Bs1);
      __syncthreads();
      f16x8 af[4], bf[4];
#pragma unroll
      for (int mi = 0; mi < 4; ++mi)
        af[mi] = *(const f16x8*)&As[((wm + (mi << 4) + llo) << 5) + (lhi << 3)];
#pragma unroll
      for (int ni = 0; ni < 4; ++ni)
        bf[ni] = *(const f16x8*)&Bs[((wn + (ni << 4) + llo) << 5) + (lhi << 3)];
#pragma unroll
      for (int mi = 0; mi < 4; ++mi)
#pragma unroll
        for (int ni = 0; ni < 4; ++ni)
          acc[mi][ni] = __builtin_amdgcn_mfma_f32_16x16x32_f16(af[mi], bf[ni], acc[mi][ni], 0, 0, 0);
    }
  }
#pragma unroll
  for (int mi = 0; mi < 4; ++mi) {
    const int row0 = (bm << 7) + wm + (mi << 4) + (lhi << 2);
#pragma unroll
    for (int ni = 0; ni < 4; ++ni) {
      const int col = (bn << 7) + wn + (ni << 4) + llo;
      _Float16* p = qkv + (size_t)row0 * 1536 + col;
#pragma unroll
      for (int r = 0; r < 4; ++r) p[(size_t)r * 1536] = (_Float16)acc[mi][ni][r];
    }
  }
}

// ---------------- depthwise k=3 conv over T + per-channel sum of squares ----------------
__global__ __launch_bounds__(256) void dwconv_k(
    const _Float16* __restrict__ qkv, const float* __restrict__ w3,
    _Float16* __restrict__ qkvc, float* __restrict__ norms) {
  int c = (blockIdx.y << 8) + threadIdx.x;      // 0..1535
  int bt = blockIdx.x;                          // b*64 + tt
  int b = bt >> 6;
  int t0 = (bt & 63) << 6;
  const _Float16* base = qkv + ((size_t)((b << 12) + t0)) * 1536 + c;
  _Float16* obase = qkvc + ((size_t)((b << 12) + t0)) * 1536 + c;
  float w0 = w3[c * 3 + 0], w1 = w3[c * 3 + 1], w2 = w3[c * 3 + 2];
  float prev = (t0 == 0) ? 0.f : (float)base[-1536];
  float cur = (float)base[0];
  float ss = 0.f;
#pragma unroll 4
  for (int i = 0; i < 64; ++i) {
    float nxt = (t0 + i == 4095) ? 0.f : (float)base[(size_t)(i + 1) * 1536];
    float o = prev * w0 + cur * w1 + nxt * w2;
    _Float16 oh = (_Float16)o;
    obase[(size_t)i * 1536] = oh;
    float of = (float)oh;
    ss += of * of;
    prev = cur; cur = nxt;
  }
  atomicAdd(&norms[b * 1536 + c], ss);
}

// ---------------- attention: partial Gram G[c][d] = sum_t q_c k_d ----------------
__global__ __launch_bounds__(256) void attn_gram_k(
    const _Float16* __restrict__ qkvc, float* __restrict__ Gbuf) {
  int bh = blockIdx.x;  int b = bh >> 3, h = bh & 7;
  int tq = blockIdx.y;                           // quarter of T
  __shared__ float qb[64][64];
  __shared__ float kb[64][64];
  float acc[4][4] = {};
  int cr = threadIdx.x >> 4, dc = threadIdx.x & 15;
  int coff = h << 6;
  for (int ch = 0; ch < 16; ++ch) {
    int tb = (tq << 10) + (ch << 6);
    __syncthreads();
#pragma unroll
    for (int i = 0; i < 16; ++i) {
      int idx = (i << 8) + threadIdx.x;
      int tl = idx >> 6, c = idx & 63;
      const _Float16* g = qkvc + ((size_t)((b << 12) + tb + tl)) * 1536 + coff + c;
      qb[tl][c] = (float)g[0];
      kb[tl][c] = (float)g[512];
    }
    __syncthreads();
#pragma unroll 8
    for (int tl = 0; tl < 64; ++tl) {
      float4 qv = *(const float4*)&qb[tl][cr << 2];
      float4 kv = *(const float4*)&kb[tl][dc << 2];
      float qa[4] = {qv.x, qv.y, qv.z, qv.w};
      float ka[4] = {kv.x, kv.y, kv.z, kv.w};
#pragma unroll
      for (int i = 0; i < 4; ++i)
#pragma unroll
        for (int j = 0; j < 4; ++j) acc[i][j] += qa[i] * ka[j];
    }
  }
  float* Gp = Gbuf + ((size_t)bh << 12);
#pragma unroll
  for (int i = 0; i < 4; ++i)
#pragma unroll
    for (int j = 0; j < 4; ++j)
      atomicAdd(&Gp[((cr << 2) + i) * 64 + (dc << 2) + j], acc[i][j]);
}

// ---------------- softmax over d with L2-norm scaling + temperature ----------------
__global__ void attn_softmax_k(
    const float* __restrict__ Gbuf, const float* __restrict__ norms,
    const float* __restrict__ temp, float* __restrict__ attn) {
  int bh = blockIdx.x;  int b = bh >> 3, h = bh & 7;
  int c = threadIdx.x;                           // 64 threads
  __shared__ float nk[64];
  float nq = fmaxf(sqrtf(norms[b * 1536 + (h << 6) + c]), 1e-12f);
  nk[c] = fmaxf(sqrtf(norms[b * 1536 + 512 + (h << 6) + c]), 1e-12f);
  __syncthreads();
  float inq = temp[h] / nq;
  const float* Gp = Gbuf + ((size_t)bh << 12) + c * 64;
  float mx = -3.0e38f;
  for (int d = 0; d < 64; ++d) mx = fmaxf(mx, Gp[d] / nk[d] * inq);
  float s = 0.f;
  for (int d = 0; d < 64; ++d) s += expf(Gp[d] / nk[d] * inq - mx);
  float inv = 1.0f / s;
  float* op = attn + ((size_t)bh << 12) + c * 64;
  for (int d = 0; d < 64; ++d) op[d] = expf(Gp[d] / nk[d] * inq - mx) * inv;
}

// ---------------- out_att: out[b,t,h*64+c] = sum_e attn[c][e] * v[e][t] ----------------
__global__ __launch_bounds__(256) void attn_out_k(
    const _Float16* __restrict__ qkvc, const float* __restrict__ attn,
    float* __restrict__ out) {
  int blk = blockIdx.x;                          // ((b*8+h)*32 + tt)
  int tt = blk & 31, h = (blk >> 5) & 7, b = blk >> 8;
  int t0 = tt << 7;                              // 128 t per block
  __shared__ float atT[64][68];                  // [e][c]
  __shared__ float vbT[64][132];                 // [e][t]
  int tid = threadIdx.x;
  const float* ap = attn + ((size_t)((b << 3) + h) << 12);
#pragma unroll
  for (int i = 0; i < 16; ++i) {
    int idx = (i << 8) + tid;  int c2 = idx >> 6, e = idx & 63;
    atT[e][c2] = ap[idx];
  }
#pragma unroll
  for (int i = 0; i < 32; ++i) {
    int idx = (i << 8) + tid;  int t = idx >> 6, e = idx & 63;
    vbT[e][t] = (float)qkvc[((size_t)((b << 12) + t0 + t)) * 1536 + 1024 + (h << 6) + e];
  }
  __syncthreads();
  int tg = tid >> 4, cg = tid & 15;              // 8 t x 4 c per thread
  float acc[8][4] = {};
#pragma unroll 2
  for (int e = 0; e < 64; ++e) {
    float4 av = *(const float4*)&atT[e][cg << 2];
    float4 v0 = *(const float4*)&vbT[e][tg << 3];
    float4 v1 = *(const float4*)&vbT[e][(tg << 3) + 4];
    float va[8] = {v0.x, v0.y, v0.z, v0.w, v1.x, v1.y, v1.z, v1.w};
    float aa[4] = {av.x, av.y, av.z, av.w};
#pragma unroll
    for (int j = 0; j < 8; ++j)
#pragma unroll
      for (int i = 0; i < 4; ++i) acc[j][i] += va[j] * aa[i];
  }
#pragma unroll
  for (int j = 0; j < 8; ++j) {
    int t = t0 + (tg << 3) + j;
    float4 st = make_float4(acc[j][0], acc[j][1], acc[j][2], acc[j][3]);
    *(float4*)&out[(((size_t)((b << 12) + t)) << 9) + (h << 6) + (cg << 2)] = st;
  }
}

// ---------------- fc branch (grouped conv) + regional ctx, accumulated into out ----------------
__global__ __launch_bounds__(256) void conv_branch_k(
    const _Float16* __restrict__ qkvc, const float* __restrict__ x,
    const float* __restrict__ wfc, const float* __restrict__ bfc,
    const float* __restrict__ wdep, const float* __restrict__ bdep,
    const float* __restrict__ w1, const float* __restrict__ w2,
    float* __restrict__ out) {
  __shared__ float fst[10][576];    // f for t in [t0-1, t0+8]
  __shared__ float c1st[12][512];   // relu(conv3(x)) for tp in [t0-2, t0+9]
  __shared__ float wfcs[216];
  __shared__ float bfcs[9];
  int b = blockIdx.x >> 9;
  int t0 = (blockIdx.x & 511) << 3;              // 8 t per block
  int tid = threadIdx.x;
  if (tid < 216) wfcs[tid] = wfc[tid];
  if (tid < 9) bfcs[tid] = bfc[tid];
  __syncthreads();
  // phase 1: f[t][u] = b_fc[u>>6] + sum_m qkvc[t, m*64+(u&63)] * W_fc[m, u>>6]
  for (int idx = tid; idx < 10 * 576; idx += 256) {
    int tl = idx / 576;
    int u = idx - tl * 576;
    int t = t0 - 1 + tl;
    float v = 0.f;
    if (t >= 0 && t < 4096) {
      int c = u & 63, n = u >> 6;
      const _Float16* q = qkvc + ((size_t)((b << 12) + t)) * 1536 + c;
      float s = bfcs[n];
#pragma unroll
      for (int m = 0; m < 24; ++m) s += (float)q[m << 6] * wfcs[m * 9 + n];
      v = s;
    }
    fst[tl][u] = v;
  }
  // phase 2: ctx1 = relu(conv3(x)), zero outside valid t (outer conv's zero pad)
  for (int idx = tid; idx < 12 * 512; idx += 256) {
    int tl = idx >> 9, d = idx & 511;
    int tp = t0 - 2 + tl;
    float v = 0.f;
    if (tp >= 0 && tp < 4096) {
      const float* xb = x + ((size_t)((b << 12) + tp)) * 512 + d;
      float a0 = (tp == 0) ? 0.f : xb[-512];
      float a1 = xb[0];
      float a2 = (tp == 4095) ? 0.f : xb[512];
      v = fmaxf(a0 * w1[d * 3] + a1 * w1[d * 3 + 1] + a2 * w1[d * 3 + 2], 0.f);
    }
    c1st[tl][d] = v;
  }
  __syncthreads();
  // phase 3: grouped conv (9 in-ch, k=3) + conv5(ctx1), add into out
  for (int dc = 0; dc < 2; ++dc) {
    int o = (dc << 8) + tid;
    int g9 = (o >> 3) * 9;
    float wd[27];
#pragma unroll
    for (int q = 0; q < 27; ++q) wd[q] = wdep[o * 27 + q];
    float w2r[5];
#pragma unroll
    for (int p = 0; p < 5; ++p) w2r[p] = w2[o * 5 + p];
    float bd = bdep[o];
    for (int tl = 0; tl < 8; ++tl) {
      float s = bd;
#pragma unroll
      for (int i = 0; i < 9; ++i)
        s += fst[tl][g9 + i] * wd[i * 3 + 0] +
             fst[tl + 1][g9 + i] * wd[i * 3 + 1] +
             fst[tl + 2][g9 + i] * wd[i * 3 + 2];
#pragma unroll
      for (int p = 0; p < 5; ++p) s += c1st[tl + p][o] * w2r[p];
      size_t oi = ((size_t)((b << 12) + t0 + tl)) * 512 + o;
      out[oi] += s;
    }
  }
}

extern "C" void kernel_launch(void* const* d_in, const int* in_sizes, int n_in,
                              void* d_out, int out_size, void* d_ws, size_t ws_size,
                              hipStream_t stream) {
  (void)in_sizes; (void)n_in; (void)out_size; (void)ws_size;
  const float* x        = (const float*)d_in[0];
  const float* W_qkv    = (const float*)d_in[1];
  const float* w_qkv_dw = (const float*)d_in[2];
  const float* w_ctx1   = (const float*)d_in[3];
  const float* w_ctx2   = (const float*)d_in[4];
  const float* W_fc     = (const float*)d_in[5];
  const float* b_fc     = (const float*)d_in[6];
  const float* w_dep    = (const float*)d_in[7];
  const float* b_dep    = (const float*)d_in[8];
  const float* temperature = (const float*)d_in[9];
  float* out = (float*)d_out;

  // workspace layout (peak ~197 MB):
  //   [0,   96M)   x splits (xhi/xlo/xhis)  -- dead after gemm; qkvc16 overlays
  //   [96M, 99M)   whi/wlos                 -- dead after gemm
  //   [99M, 195M)  qkv16 (f16 32768x1536)
  //   [195M, ...)  Gbuf (1M), attn (1M), norms (48K)
  char* ws = (char*)d_ws;
  _Float16* xhi  = (_Float16*)(ws);
  _Float16* xlo  = (_Float16*)(ws + 33554432);
  _Float16* xhis = (_Float16*)(ws + 67108864);
  _Float16* whi  = (_Float16*)(ws + 100663296);
  _Float16* wlos = (_Float16*)(ws + 102236160);
  _Float16* qkv16  = (_Float16*)(ws + 103809024);
  _Float16* qkvc16 = (_Float16*)(ws);            // overlays x splits (dead)
  char* tail = ws + 204472320;
  float* Gbuf  = (float*)(tail);
  float* attn  = (float*)(tail + 1048576);
  float* norms = (float*)(tail + 2097152);

  zero_k<<<1024, 256, 0, stream>>>(Gbuf, norms);
  split_x_k<<<16384, 256, 0, stream>>>(x, xhi, xlo, xhis);
  split_wt_k<<<3072, 256, 0, stream>>>(W_qkv, whi, wlos);
  gemm_qkv_k<<<dim3(12, 256), 256, 0, stream>>>(xhi, xlo, xhis, whi, wlos, qkv16);
  dwconv_k<<<dim3(512, 6), 256, 0, stream>>>(qkv16, w_qkv_dw, qkvc16, norms);
  attn_gram_k<<<dim3(64, 4), 256, 0, stream>>>(qkvc16, Gbuf);
  attn_softmax_k<<<64, 64, 0, stream>>>(Gbuf, norms, temperature, attn);
  attn_out_k<<<2048, 256, 0, stream>>>(qkvc16, attn, out);
  conv_branch_k<<<4096, 256, 0, stream>>>(qkvc16, x, W_fc, b_fc, w_dep, b_dep,
                                          w_ctx1, w_ctx2, out);
}

// Round 3
// 522.240 us; speedup vs baseline: 1.2862x; 1.2862x over previous
//
#include <hip/hip_runtime.h>

typedef __attribute__((ext_vector_type(8))) _Float16 f16x8;
typedef __attribute__((ext_vector_type(4))) _Float16 f16x4;
typedef __attribute__((ext_vector_type(4))) float f32x4;

// async global->LDS, 16B per lane; LDS dest = wave-uniform base + lane*16
__device__ inline void gl_lds16(const void* g, void* l) {
  __builtin_amdgcn_global_load_lds(
      (const __attribute__((address_space(1))) unsigned int*)g,
      (__attribute__((address_space(3))) unsigned int*)l, 16, 0, 0);
}

// ---------------- zero-init scratch (replaces hipMemsetAsync) ----------------
__global__ __launch_bounds__(256) void zero_k(float* __restrict__ g, float* __restrict__ n) {
  int i = (blockIdx.x << 8) + threadIdx.x;
  if (i < 262144) g[i] = 0.f;
  if (i < 12288) n[i] = 0.f;
}

// ---------------- split/convert kernels ----------------
__global__ __launch_bounds__(256) void split_x_k(
    const float* __restrict__ x, _Float16* __restrict__ hi,
    _Float16* __restrict__ lo, _Float16* __restrict__ his) {
  int i = (blockIdx.x << 8) + threadIdx.x;      // one float4 each
  float4 v = ((const float4*)x)[i];
  float fs[4] = {v.x, v.y, v.z, v.w};
  f16x4 h, l, s;
#pragma unroll
  for (int j = 0; j < 4; ++j) {
    _Float16 hh = (_Float16)fs[j];
    float r = fs[j] - (float)hh;
    h[j] = hh;
    l[j] = (_Float16)r;
    s[j] = (_Float16)((float)hh * 4.8828125e-4f);  // *2^-11
  }
  *(f16x4*)&hi[(size_t)i << 2] = h;
  *(f16x4*)&lo[(size_t)i << 2] = l;
  *(f16x4*)&his[(size_t)i << 2] = s;
}

__global__ __launch_bounds__(256) void split_wt_k(
    const float* __restrict__ w, _Float16* __restrict__ hi, _Float16* __restrict__ los) {
  int idx = (blockIdx.x << 8) + threadIdx.x;    // idx = n*512 + k
  int n = idx >> 9, k = idx & 511;
  float f = w[(size_t)k * 1536 + n];
  _Float16 h = (_Float16)f;
  float r = f - (float)h;
  hi[idx] = h;
  los[idx] = (_Float16)(r * 2048.0f);           // *2^11
}

// ---------------- split-f16 MFMA GEMM: qkv16 = x @ W_qkv (f16 out) ----------------
__global__ __launch_bounds__(256) void gemm_qkv_k(
    const _Float16* __restrict__ xhi, const _Float16* __restrict__ xlo,
    const _Float16* __restrict__ xhis, const _Float16* __restrict__ whi,
    const _Float16* __restrict__ wlos, _Float16* __restrict__ qkv) {
  __shared__ _Float16 As[128 * 32];   // [m][k], 64B rows
  __shared__ _Float16 Bs[128 * 32];   // [n][k]
  const int tid = threadIdx.x;
  const int wave = tid >> 6, lane = tid & 63;
  const int bn = blockIdx.x;          // 0..11
  const int bm = blockIdx.y;          // 0..255
  const int wm = (wave >> 1) << 6, wn = (wave & 1) << 6;
  const int lhi = lane >> 4, llo = lane & 15;

  f32x4 zero = {};
  f32x4 acc[4][4];
#pragma unroll
  for (int i = 0; i < 4; ++i)
#pragma unroll
    for (int j = 0; j < 4; ++j) acc[i][j] = zero;

  const int arow = (bm << 7) + (wave << 5) + (lane >> 2);
  const int brow = (bn << 7) + (wave << 5) + (lane >> 2);
  const int kc = (lane & 3) << 3;
  _Float16* As0 = &As[(wave << 5) << 5];
  _Float16* As1 = &As[((wave << 5) + 16) << 5];
  _Float16* Bs0 = &Bs[(wave << 5) << 5];
  _Float16* Bs1 = &Bs[((wave << 5) + 16) << 5];

  for (int seg = 0; seg < 3; ++seg) {
    const _Float16* Ag = (seg == 0) ? xhi : ((seg == 1) ? xlo : xhis);
    const _Float16* Bg = (seg == 2) ? wlos : whi;
    const _Float16* a0 = Ag + ((size_t)arow << 9) + kc;
    const _Float16* a1 = Ag + ((size_t)(arow + 16) << 9) + kc;
    const _Float16* b0 = Bg + ((size_t)brow << 9) + kc;
    const _Float16* b1 = Bg + ((size_t)(brow + 16) << 9) + kc;
    for (int ks = 0; ks < 16; ++ks) {
      const int k0 = ks << 5;
      __syncthreads();
      gl_lds16(a0 + k0, As0);
      gl_lds16(a1 + k0, As1);
      gl_lds16(b0 + k0, Bs0);
      gl_lds16(b1 + k0, Bs1);
      __syncthreads();
      f16x8 af[4], bf[4];
#pragma unroll
      for (int mi = 0; mi < 4; ++mi)
        af[mi] = *(const f16x8*)&As[((wm + (mi << 4) + llo) << 5) + (lhi << 3)];
#pragma unroll
      for (int ni = 0; ni < 4; ++ni)
        bf[ni] = *(const f16x8*)&Bs[((wn + (ni << 4) + llo) << 5) + (lhi << 3)];
#pragma unroll
      for (int mi = 0; mi < 4; ++mi)
#pragma unroll
        for (int ni = 0; ni < 4; ++ni)
          acc[mi][ni] = __builtin_amdgcn_mfma_f32_16x16x32_f16(af[mi], bf[ni], acc[mi][ni], 0, 0, 0);
    }
  }
#pragma unroll
  for (int mi = 0; mi < 4; ++mi) {
    const int row0 = (bm << 7) + wm + (mi << 4) + (lhi << 2);
#pragma unroll
    for (int ni = 0; ni < 4; ++ni) {
      const int col = (bn << 7) + wn + (ni << 4) + llo;
      _Float16* p = qkv + (size_t)row0 * 1536 + col;
#pragma unroll
      for (int r = 0; r < 4; ++r) p[(size_t)r * 1536] = (_Float16)acc[mi][ni][r];
    }
  }
}

// ---------------- depthwise k=3 conv over T + per-channel sum of squares ----------------
__global__ __launch_bounds__(256) void dwconv_k(
    const _Float16* __restrict__ qkv, const float* __restrict__ w3,
    _Float16* __restrict__ qkvc, float* __restrict__ norms) {
  int c = (blockIdx.y << 8) + threadIdx.x;      // 0..1535
  int bt = blockIdx.x;                          // b*64 + tt
  int b = bt >> 6;
  int t0 = (bt & 63) << 6;
  const _Float16* base = qkv + ((size_t)((b << 12) + t0)) * 1536 + c;
  _Float16* obase = qkvc + ((size_t)((b << 12) + t0)) * 1536 + c;
  float w0 = w3[c * 3 + 0], w1 = w3[c * 3 + 1], w2 = w3[c * 3 + 2];
  float prev = (t0 == 0) ? 0.f : (float)base[-1536];
  float cur = (float)base[0];
  float ss = 0.f;
#pragma unroll 4
  for (int i = 0; i < 64; ++i) {
    float nxt = (t0 + i == 4095) ? 0.f : (float)base[(size_t)(i + 1) * 1536];
    float o = prev * w0 + cur * w1 + nxt * w2;
    _Float16 oh = (_Float16)o;
    obase[(size_t)i * 1536] = oh;
    float of = (float)oh;
    ss += of * of;
    prev = cur; cur = nxt;
  }
  atomicAdd(&norms[b * 1536 + c], ss);
}

// ---------------- attention: partial Gram G[c][d] = sum_t q_c k_d ----------------
__global__ __launch_bounds__(256) void attn_gram_k(
    const _Float16* __restrict__ qkvc, float* __restrict__ Gbuf) {
  int bh = blockIdx.x;  int b = bh >> 3, h = bh & 7;
  int tq = blockIdx.y;                           // quarter of T
  __shared__ float qb[64][64];
  __shared__ float kb[64][64];
  float acc[4][4] = {};
  int cr = threadIdx.x >> 4, dc = threadIdx.x & 15;
  int coff = h << 6;
  for (int ch = 0; ch < 16; ++ch) {
    int tb = (tq << 10) + (ch << 6);
    __syncthreads();
#pragma unroll
    for (int i = 0; i < 16; ++i) {
      int idx = (i << 8) + threadIdx.x;
      int tl = idx >> 6, c = idx & 63;
      const _Float16* g = qkvc + ((size_t)((b << 12) + tb + tl)) * 1536 + coff + c;
      qb[tl][c] = (float)g[0];
      kb[tl][c] = (float)g[512];
    }
    __syncthreads();
#pragma unroll 8
    for (int tl = 0; tl < 64; ++tl) {
      float4 qv = *(const float4*)&qb[tl][cr << 2];
      float4 kv = *(const float4*)&kb[tl][dc << 2];
      float qa[4] = {qv.x, qv.y, qv.z, qv.w};
      float ka[4] = {kv.x, kv.y, kv.z, kv.w};
#pragma unroll
      for (int i = 0; i < 4; ++i)
#pragma unroll
        for (int j = 0; j < 4; ++j) acc[i][j] += qa[i] * ka[j];
    }
  }
  float* Gp = Gbuf + ((size_t)bh << 12);
#pragma unroll
  for (int i = 0; i < 4; ++i)
#pragma unroll
    for (int j = 0; j < 4; ++j)
      atomicAdd(&Gp[((cr << 2) + i) * 64 + (dc << 2) + j], acc[i][j]);
}

// ---------------- softmax over d with L2-norm scaling + temperature ----------------
__global__ void attn_softmax_k(
    const float* __restrict__ Gbuf, const float* __restrict__ norms,
    const float* __restrict__ temp, float* __restrict__ attn) {
  int bh = blockIdx.x;  int b = bh >> 3, h = bh & 7;
  int c = threadIdx.x;                           // 64 threads
  __shared__ float nk[64];
  float nq = fmaxf(sqrtf(norms[b * 1536 + (h << 6) + c]), 1e-12f);
  nk[c] = fmaxf(sqrtf(norms[b * 1536 + 512 + (h << 6) + c]), 1e-12f);
  __syncthreads();
  float inq = temp[h] / nq;
  const float* Gp = Gbuf + ((size_t)bh << 12) + c * 64;
  float mx = -3.0e38f;
  for (int d = 0; d < 64; ++d) mx = fmaxf(mx, Gp[d] / nk[d] * inq);
  float s = 0.f;
  for (int d = 0; d < 64; ++d) s += expf(Gp[d] / nk[d] * inq - mx);
  float inv = 1.0f / s;
  float* op = attn + ((size_t)bh << 12) + c * 64;
  for (int d = 0; d < 64; ++d) op[d] = expf(Gp[d] / nk[d] * inq - mx) * inv;
}

// ---------------- out_att: out[b,t,h*64+c] = sum_e attn[c][e] * v[e][t] ----------------
__global__ __launch_bounds__(256) void attn_out_k(
    const _Float16* __restrict__ qkvc, const float* __restrict__ attn,
    float* __restrict__ out) {
  int blk = blockIdx.x;                          // ((b*8+h)*32 + tt)
  int tt = blk & 31, h = (blk >> 5) & 7, b = blk >> 8;
  int t0 = tt << 7;                              // 128 t per block
  __shared__ float atT[64][68];                  // [e][c]
  __shared__ float vbT[64][132];                 // [e][t]
  int tid = threadIdx.x;
  const float* ap = attn + ((size_t)((b << 3) + h) << 12);
#pragma unroll
  for (int i = 0; i < 16; ++i) {
    int idx = (i << 8) + tid;  int c2 = idx >> 6, e = idx & 63;
    atT[e][c2] = ap[idx];
  }
#pragma unroll
  for (int i = 0; i < 32; ++i) {
    int idx = (i << 8) + tid;  int t = idx >> 6, e = idx & 63;
    vbT[e][t] = (float)qkvc[((size_t)((b << 12) + t0 + t)) * 1536 + 1024 + (h << 6) + e];
  }
  __syncthreads();
  int tg = tid >> 4, cg = tid & 15;              // 8 t x 4 c per thread
  float acc[8][4] = {};
#pragma unroll 2
  for (int e = 0; e < 64; ++e) {
    float4 av = *(const float4*)&atT[e][cg << 2];
    float4 v0 = *(const float4*)&vbT[e][tg << 3];
    float4 v1 = *(const float4*)&vbT[e][(tg << 3) + 4];
    float va[8] = {v0.x, v0.y, v0.z, v0.w, v1.x, v1.y, v1.z, v1.w};
    float aa[4] = {av.x, av.y, av.z, av.w};
#pragma unroll
    for (int j = 0; j < 8; ++j)
#pragma unroll
      for (int i = 0; i < 4; ++i) acc[j][i] += va[j] * aa[i];
  }
#pragma unroll
  for (int j = 0; j < 8; ++j) {
    int t = t0 + (tg << 3) + j;
    float4 st = make_float4(acc[j][0], acc[j][1], acc[j][2], acc[j][3]);
    *(float4*)&out[(((size_t)((b << 12) + t)) << 9) + (h << 6) + (cg << 2)] = st;
  }
}

// ---------------- fc: f[b,t,n*64+c] = b_fc[n] + sum_m qkvc[b,t,m*64+c]*W_fc[m,n] ----------------
__global__ __launch_bounds__(256) void fc_k(
    const _Float16* __restrict__ qkvc, const float* __restrict__ wfc,
    const float* __restrict__ bfc, _Float16* __restrict__ f) {
  __shared__ float wfcs[216];
  __shared__ float bfcs[9];
  int tid = threadIdx.x;
  if (tid < 216) wfcs[tid] = wfc[tid];
  if (tid < 9) bfcs[tid] = bfc[tid];
  __syncthreads();
  int b = blockIdx.x >> 7;
  int t = ((blockIdx.x & 127) << 5) + (tid >> 3);   // 32 t per block
  int cg = tid & 7;                                  // 8-channel group
  const _Float16* q = qkvc + ((size_t)((b << 12) + t)) * 1536 + (cg << 3);
  float acc[9][8];
#pragma unroll
  for (int n = 0; n < 9; ++n) {
    float bv = bfcs[n];
#pragma unroll
    for (int j = 0; j < 8; ++j) acc[n][j] = bv;
  }
  for (int m = 0; m < 24; ++m) {
    f16x8 v = *(const f16x8*)&q[m << 6];
    float vf[8];
#pragma unroll
    for (int j = 0; j < 8; ++j) vf[j] = (float)v[j];
#pragma unroll
    for (int n = 0; n < 9; ++n) {
      float w = wfcs[m * 9 + n];
#pragma unroll
      for (int j = 0; j < 8; ++j) acc[n][j] += w * vf[j];
    }
  }
  _Float16* fp = f + ((size_t)((b << 12) + t)) * 576 + (cg << 3);
#pragma unroll
  for (int n = 0; n < 9; ++n) {
    f16x8 o;
#pragma unroll
    for (int j = 0; j < 8; ++j) o[j] = (_Float16)acc[n][j];
    *(f16x8*)&fp[n << 6] = o;
  }
}

// ---------------- grouped conv (9in->8out per group, k=3) + ctx chain, += out ----------------
__global__ __launch_bounds__(256) void conv2_k(
    const _Float16* __restrict__ f, const float* __restrict__ x,
    const float* __restrict__ wdep, const float* __restrict__ bdep,
    const float* __restrict__ w1, const float* __restrict__ w2,
    float* __restrict__ out) {
  __shared__ _Float16 fs[34][576];    // f rows t0-1 .. t0+32
  __shared__ _Float16 c1[36][512];    // ctx1 rows tp = t0-2 .. t0+33
  int b = blockIdx.x >> 7;
  int t0 = (blockIdx.x & 127) << 5;   // 32 t per block
  int tid = threadIdx.x;

  // phase A: ctx1 = relu(conv3(x)) for 36 rows (f16 in LDS)
#pragma unroll
  for (int half = 0; half < 2; ++half) {
    int d = (half << 8) + tid;
    float w10 = w1[d * 3], w11 = w1[d * 3 + 1], w12 = w1[d * 3 + 2];
    const float* xb = x + ((size_t)(b << 12)) * 512 + d;
    int tp0 = t0 - 2;
    float xm = (tp0 - 1 >= 0) ? xb[(size_t)(tp0 - 1) * 512] : 0.f;
    float xc = (tp0 >= 0 && tp0 < 4096) ? xb[(size_t)tp0 * 512] : 0.f;
    for (int tl = 0; tl < 36; ++tl) {
      int tp = tp0 + tl;
      float xp = (tp + 1 >= 0 && tp + 1 < 4096) ? xb[(size_t)(tp + 1) * 512] : 0.f;
      float v = 0.f;
      if (tp >= 0 && tp < 4096)
        v = fmaxf(xm * w10 + xc * w11 + xp * w12, 0.f);
      c1[tl][d] = (_Float16)v;
      xm = xc; xc = xp;
    }
  }
  // phase B: stage f rows t0-1 .. t0+32 (vector loads)
  for (int idx = tid; idx < 34 * 72; idx += 256) {
    int row = idx / 72, col = idx - row * 72;
    int t = t0 - 1 + row;
    f16x8 v = {};
    if (t >= 0 && t < 4096)
      v = *(const f16x8*)&f[((size_t)((b << 12) + t)) * 576 + (col << 3)];
    *(f16x8*)&fs[row][col << 3] = v;
  }
  __syncthreads();

  // phase C: per output channel, rolling-register stencil over 32 t
#pragma unroll
  for (int pass = 0; pass < 2; ++pass) {
    int o = (pass << 8) + tid;
    int g9 = (o >> 3) * 9;
    float wd[27];
#pragma unroll
    for (int q = 0; q < 27; ++q) wd[q] = wdep[o * 27 + q];
    float w2r[5];
#pragma unroll
    for (int p = 0; p < 5; ++p) w2r[p] = w2[o * 5 + p];
    float bd = bdep[o];
    float f0[9], f1[9], f2[9];
#pragma unroll
    for (int i = 0; i < 9; ++i) {
      f0[i] = (float)fs[0][g9 + i];
      f1[i] = (float)fs[1][g9 + i];
    }
    float c0 = (float)c1[0][o], cA = (float)c1[1][o], cB = (float)c1[2][o], cC = (float)c1[3][o];
    float* ob = out + ((size_t)((b << 12) + t0)) * 512 + o;
    for (int tl = 0; tl < 32; ++tl) {
      float s = bd;
#pragma unroll
      for (int i = 0; i < 9; ++i) f2[i] = (float)fs[tl + 2][g9 + i];
      float c4 = (float)c1[tl + 4][o];
#pragma unroll
      for (int i = 0; i < 9; ++i)
        s += f0[i] * wd[i * 3 + 0] + f1[i] * wd[i * 3 + 1] + f2[i] * wd[i * 3 + 2];
      s += c0 * w2r[0] + cA * w2r[1] + cB * w2r[2] + cC * w2r[3] + c4 * w2r[4];
      ob[(size_t)tl * 512] += s;
#pragma unroll
      for (int i = 0; i < 9; ++i) { f0[i] = f1[i]; f1[i] = f2[i]; }
      c0 = cA; cA = cB; cB = cC; cC = c4;
    }
  }
}

extern "C" void kernel_launch(void* const* d_in, const int* in_sizes, int n_in,
                              void* d_out, int out_size, void* d_ws, size_t ws_size,
                              hipStream_t stream) {
  (void)in_sizes; (void)n_in; (void)out_size; (void)ws_size;
  const float* x        = (const float*)d_in[0];
  const float* W_qkv    = (const float*)d_in[1];
  const float* w_qkv_dw = (const float*)d_in[2];
  const float* w_ctx1   = (const float*)d_in[3];
  const float* w_ctx2   = (const float*)d_in[4];
  const float* W_fc     = (const float*)d_in[5];
  const float* b_fc     = (const float*)d_in[6];
  const float* w_dep    = (const float*)d_in[7];
  const float* b_dep    = (const float*)d_in[8];
  const float* temperature = (const float*)d_in[9];
  float* out = (float*)d_out;

  // workspace layout (peak ~197 MB):
  //   [0,   96M)   x splits (xhi/xlo/xhis)  -- dead after gemm; qkvc16 overlays
  //   [96M, 99M)   whi/wlos                 -- dead after gemm
  //   [99M, 195M)  qkv16 (f16 32768x1536)   -- dead after dwconv; f overlays
  //   [195M, ...)  Gbuf (1M), attn (1M), norms (48K)
  char* ws = (char*)d_ws;
  _Float16* xhi  = (_Float16*)(ws);
  _Float16* xlo  = (_Float16*)(ws + 33554432);
  _Float16* xhis = (_Float16*)(ws + 67108864);
  _Float16* whi  = (_Float16*)(ws + 100663296);
  _Float16* wlos = (_Float16*)(ws + 102236160);
  _Float16* qkv16  = (_Float16*)(ws + 103809024);
  _Float16* qkvc16 = (_Float16*)(ws);            // overlays x splits (dead)
  _Float16* fbuf   = (_Float16*)(ws + 103809024); // overlays qkv16 (dead after dwconv)
  char* tail = ws + 204472320;
  float* Gbuf  = (float*)(tail);
  float* attn  = (float*)(tail + 1048576);
  float* norms = (float*)(tail + 2097152);

  zero_k<<<1024, 256, 0, stream>>>(Gbuf, norms);
  split_x_k<<<16384, 256, 0, stream>>>(x, xhi, xlo, xhis);
  split_wt_k<<<3072, 256, 0, stream>>>(W_qkv, whi, wlos);
  gemm_qkv_k<<<dim3(12, 256), 256, 0, stream>>>(xhi, xlo, xhis, whi, wlos, qkv16);
  dwconv_k<<<dim3(512, 6), 256, 0, stream>>>(qkv16, w_qkv_dw, qkvc16, norms);
  fc_k<<<1024, 256, 0, stream>>>(qkvc16, W_fc, b_fc, fbuf);
  attn_gram_k<<<dim3(64, 4), 256, 0, stream>>>(qkvc16, Gbuf);
  attn_softmax_k<<<64, 64, 0, stream>>>(Gbuf, norms, temperature, attn);
  attn_out_k<<<2048, 256, 0, stream>>>(qkvc16, attn, out);
  conv2_k<<<1024, 256, 0, stream>>>(fbuf, x, w_dep, b_dep, w_ctx1, w_ctx2, out);
}

// Round 4
// 484.126 us; speedup vs baseline: 1.3875x; 1.0787x over previous
//
#include <hip/hip_runtime.h>

typedef __attribute__((ext_vector_type(8))) _Float16 f16x8;
typedef __attribute__((ext_vector_type(4))) _Float16 f16x4;
typedef __attribute__((ext_vector_type(4))) float f32x4;

// async global->LDS, 16B per lane; LDS dest = wave-uniform base + lane*16
__device__ inline void gl_lds16(const void* g, void* l) {
  __builtin_amdgcn_global_load_lds(
      (const __attribute__((address_space(1))) unsigned int*)g,
      (__attribute__((address_space(3))) unsigned int*)l, 16, 0, 0);
}

// ---------------- zero-init scratch (replaces hipMemsetAsync) ----------------
__global__ __launch_bounds__(256) void zero_k(float* __restrict__ g, float* __restrict__ n) {
  int i = (blockIdx.x << 8) + threadIdx.x;
  if (i < 262144) g[i] = 0.f;
  if (i < 12288) n[i] = 0.f;
}

// ---------------- split/convert kernels ----------------
__global__ __launch_bounds__(256) void split_x_k(
    const float* __restrict__ x, _Float16* __restrict__ hi,
    _Float16* __restrict__ lo, _Float16* __restrict__ his) {
  int i = (blockIdx.x << 8) + threadIdx.x;      // one float4 each
  float4 v = ((const float4*)x)[i];
  float fs[4] = {v.x, v.y, v.z, v.w};
  f16x4 h, l, s;
#pragma unroll
  for (int j = 0; j < 4; ++j) {
    _Float16 hh = (_Float16)fs[j];
    float r = fs[j] - (float)hh;
    h[j] = hh;
    l[j] = (_Float16)r;
    s[j] = (_Float16)((float)hh * 4.8828125e-4f);  // *2^-11
  }
  *(f16x4*)&hi[(size_t)i << 2] = h;
  *(f16x4*)&lo[(size_t)i << 2] = l;
  *(f16x4*)&his[(size_t)i << 2] = s;
}

__global__ __launch_bounds__(256) void split_wt_k(
    const float* __restrict__ w, _Float16* __restrict__ hi, _Float16* __restrict__ los) {
  int idx = (blockIdx.x << 8) + threadIdx.x;    // idx = n*512 + k
  int n = idx >> 9, k = idx & 511;
  float f = w[(size_t)k * 1536 + n];
  _Float16 h = (_Float16)f;
  float r = f - (float)h;
  hi[idx] = h;
  los[idx] = (_Float16)(r * 2048.0f);           // *2^11
}

// ---------------- split-f16 MFMA GEMM: qkv16 = x @ W_qkv (f16 out) ----------------
// 128x128 tile, BK=32, 2-phase double-buffered LDS with counted vmcnt (T3/T4-lite)
// + bijective XCD-chunked block swizzle (T1).
__global__ __launch_bounds__(256) void gemm_qkv_k(
    const _Float16* __restrict__ xhi, const _Float16* __restrict__ xlo,
    const _Float16* __restrict__ xhis, const _Float16* __restrict__ whi,
    const _Float16* __restrict__ wlos, _Float16* __restrict__ qkv) {
  __shared__ _Float16 As[2][128 * 32];   // [buf][m][k], 64B rows
  __shared__ _Float16 Bs[2][128 * 32];   // [buf][n][k]
  const int tid = threadIdx.x;
  const int wave = tid >> 6, lane = tid & 63;
  // T1: nwg=3072 divisible by 8 -> wg = (orig%8)*384 + orig/8.
  // Each XCD gets 384 consecutive wg = 32 disjoint bm panels (A read once/XCD).
  const int orig = blockIdx.x;
  const int wg = ((orig & 7) * 384) + (orig >> 3);
  const int bm = wg / 12;               // 0..255
  const int bn = wg - bm * 12;          // 0..11
  const int wm = (wave >> 1) << 6, wn = (wave & 1) << 6;
  const int lhi = lane >> 4, llo = lane & 15;

  f32x4 zero = {};
  f32x4 acc[4][4];
#pragma unroll
  for (int i = 0; i < 4; ++i)
#pragma unroll
    for (int j = 0; j < 4; ++j) acc[i][j] = zero;

  const int srowA = (bm << 7) + (wave << 5) + (lane >> 2);
  const int srowB = (bn << 7) + (wave << 5) + (lane >> 2);
  const int kc = (lane & 3) << 3;
  const size_t aoff0 = ((size_t)srowA << 9) + kc;
  const size_t aoff1 = ((size_t)(srowA + 16) << 9) + kc;
  const size_t boff0 = ((size_t)srowB << 9) + kc;
  const size_t boff1 = ((size_t)(srowB + 16) << 9) + kc;
  const int wb0 = (wave << 5) << 5;           // wave-uniform LDS dest offsets
  const int wb1 = ((wave << 5) + 16) << 5;

  auto stage = [&](int buf, int kk) {
    const int s = kk >> 4;                    // segment 0..2
    const int k0 = (kk & 15) << 5;
    const _Float16* Ag = (s == 0) ? xhi : ((s == 1) ? xlo : xhis);
    const _Float16* Bg = (s == 2) ? wlos : whi;
    gl_lds16(Ag + aoff0 + k0, &As[buf][wb0]);
    gl_lds16(Ag + aoff1 + k0, &As[buf][wb1]);
    gl_lds16(Bg + boff0 + k0, &Bs[buf][wb0]);
    gl_lds16(Bg + boff1 + k0, &Bs[buf][wb1]);
  };

  stage(0, 0);
  for (int kk = 0; kk < 48; ++kk) {
    const int cur = kk & 1;
    if (kk < 47) {
      stage(cur ^ 1, kk + 1);                 // prefetch next K-tile, stays in flight
      asm volatile("s_waitcnt vmcnt(4)" ::: "memory");  // only current tile's 4 loads done
    } else {
      asm volatile("s_waitcnt vmcnt(0)" ::: "memory");
    }
    __builtin_amdgcn_s_barrier();             // raw barrier: no implicit vmcnt(0) drain
    __builtin_amdgcn_sched_barrier(0);
    f16x8 af[4], bf[4];
#pragma unroll
    for (int mi = 0; mi < 4; ++mi)
      af[mi] = *(const f16x8*)&As[cur][((wm + (mi << 4) + llo) << 5) + (lhi << 3)];
#pragma unroll
    for (int ni = 0; ni < 4; ++ni)
      bf[ni] = *(const f16x8*)&Bs[cur][((wn + (ni << 4) + llo) << 5) + (lhi << 3)];
#pragma unroll
    for (int mi = 0; mi < 4; ++mi)
#pragma unroll
      for (int ni = 0; ni < 4; ++ni)
        acc[mi][ni] = __builtin_amdgcn_mfma_f32_16x16x32_f16(af[mi], bf[ni], acc[mi][ni], 0, 0, 0);
    __builtin_amdgcn_sched_barrier(0);
    __builtin_amdgcn_s_barrier();             // all reads of buf[cur] done before restage
  }
#pragma unroll
  for (int mi = 0; mi < 4; ++mi) {
    const int row0 = (bm << 7) + wm + (mi << 4) + (lhi << 2);
#pragma unroll
    for (int ni = 0; ni < 4; ++ni) {
      const int col = (bn << 7) + wn + (ni << 4) + llo;
      _Float16* p = qkv + (size_t)row0 * 1536 + col;
#pragma unroll
      for (int r = 0; r < 4; ++r) p[(size_t)r * 1536] = (_Float16)acc[mi][ni][r];
    }
  }
}

// ---------------- depthwise k=3 conv over T + per-channel sum of squares ----------------
__global__ __launch_bounds__(256) void dwconv_k(
    const _Float16* __restrict__ qkv, const float* __restrict__ w3,
    _Float16* __restrict__ qkvc, float* __restrict__ norms) {
  int c = (blockIdx.y << 8) + threadIdx.x;      // 0..1535
  int bt = blockIdx.x;                          // b*64 + tt
  int b = bt >> 6;
  int t0 = (bt & 63) << 6;
  const _Float16* base = qkv + ((size_t)((b << 12) + t0)) * 1536 + c;
  _Float16* obase = qkvc + ((size_t)((b << 12) + t0)) * 1536 + c;
  float w0 = w3[c * 3 + 0], w1 = w3[c * 3 + 1], w2 = w3[c * 3 + 2];
  float prev = (t0 == 0) ? 0.f : (float)base[-1536];
  float cur = (float)base[0];
  float ss = 0.f;
#pragma unroll 4
  for (int i = 0; i < 64; ++i) {
    float nxt = (t0 + i == 4095) ? 0.f : (float)base[(size_t)(i + 1) * 1536];
    float o = prev * w0 + cur * w1 + nxt * w2;
    _Float16 oh = (_Float16)o;
    obase[(size_t)i * 1536] = oh;
    float of = (float)oh;
    ss += of * of;
    prev = cur; cur = nxt;
  }
  atomicAdd(&norms[b * 1536 + c], ss);
}

// ---------------- attention: partial Gram G[c][d] = sum_t q_c k_d ----------------
__global__ __launch_bounds__(256) void attn_gram_k(
    const _Float16* __restrict__ qkvc, float* __restrict__ Gbuf) {
  int bh = blockIdx.x;  int b = bh >> 3, h = bh & 7;
  int tq = blockIdx.y;                           // quarter of T
  __shared__ float qb[64][64];
  __shared__ float kb[64][64];
  float acc[4][4] = {};
  int cr = threadIdx.x >> 4, dc = threadIdx.x & 15;
  int coff = h << 6;
  for (int ch = 0; ch < 16; ++ch) {
    int tb = (tq << 10) + (ch << 6);
    __syncthreads();
#pragma unroll
    for (int i = 0; i < 16; ++i) {
      int idx = (i << 8) + threadIdx.x;
      int tl = idx >> 6, c = idx & 63;
      const _Float16* g = qkvc + ((size_t)((b << 12) + tb + tl)) * 1536 + coff + c;
      qb[tl][c] = (float)g[0];
      kb[tl][c] = (float)g[512];
    }
    __syncthreads();
#pragma unroll 8
    for (int tl = 0; tl < 64; ++tl) {
      float4 qv = *(const float4*)&qb[tl][cr << 2];
      float4 kv = *(const float4*)&kb[tl][dc << 2];
      float qa[4] = {qv.x, qv.y, qv.z, qv.w};
      float ka[4] = {kv.x, kv.y, kv.z, kv.w};
#pragma unroll
      for (int i = 0; i < 4; ++i)
#pragma unroll
        for (int j = 0; j < 4; ++j) acc[i][j] += qa[i] * ka[j];
    }
  }
  float* Gp = Gbuf + ((size_t)bh << 12);
#pragma unroll
  for (int i = 0; i < 4; ++i)
#pragma unroll
    for (int j = 0; j < 4; ++j)
      atomicAdd(&Gp[((cr << 2) + i) * 64 + (dc << 2) + j], acc[i][j]);
}

// ---------------- softmax over d with L2-norm scaling + temperature ----------------
__global__ void attn_softmax_k(
    const float* __restrict__ Gbuf, const float* __restrict__ norms,
    const float* __restrict__ temp, float* __restrict__ attn) {
  int bh = blockIdx.x;  int b = bh >> 3, h = bh & 7;
  int c = threadIdx.x;                           // 64 threads
  __shared__ float nk[64];
  float nq = fmaxf(sqrtf(norms[b * 1536 + (h << 6) + c]), 1e-12f);
  nk[c] = fmaxf(sqrtf(norms[b * 1536 + 512 + (h << 6) + c]), 1e-12f);
  __syncthreads();
  float inq = temp[h] / nq;
  const float* Gp = Gbuf + ((size_t)bh << 12) + c * 64;
  float mx = -3.0e38f;
  for (int d = 0; d < 64; ++d) mx = fmaxf(mx, Gp[d] / nk[d] * inq);
  float s = 0.f;
  for (int d = 0; d < 64; ++d) s += expf(Gp[d] / nk[d] * inq - mx);
  float inv = 1.0f / s;
  float* op = attn + ((size_t)bh << 12) + c * 64;
  for (int d = 0; d < 64; ++d) op[d] = expf(Gp[d] / nk[d] * inq - mx) * inv;
}

// ---------------- out_att: out[b,t,h*64+c] = sum_e attn[c][e] * v[e][t] ----------------
__global__ __launch_bounds__(256) void attn_out_k(
    const _Float16* __restrict__ qkvc, const float* __restrict__ attn,
    float* __restrict__ out) {
  int blk = blockIdx.x;                          // ((b*8+h)*32 + tt)
  int tt = blk & 31, h = (blk >> 5) & 7, b = blk >> 8;
  int t0 = tt << 7;                              // 128 t per block
  __shared__ float atT[64][68];                  // [e][c]
  __shared__ float vbT[64][132];                 // [e][t]
  int tid = threadIdx.x;
  const float* ap = attn + ((size_t)((b << 3) + h) << 12);
#pragma unroll
  for (int i = 0; i < 16; ++i) {
    int idx = (i << 8) + tid;  int c2 = idx >> 6, e = idx & 63;
    atT[e][c2] = ap[idx];
  }
#pragma unroll
  for (int i = 0; i < 32; ++i) {
    int idx = (i << 8) + tid;  int t = idx >> 6, e = idx & 63;
    vbT[e][t] = (float)qkvc[((size_t)((b << 12) + t0 + t)) * 1536 + 1024 + (h << 6) + e];
  }
  __syncthreads();
  int tg = tid >> 4, cg = tid & 15;              // 8 t x 4 c per thread
  float acc[8][4] = {};
#pragma unroll 2
  for (int e = 0; e < 64; ++e) {
    float4 av = *(const float4*)&atT[e][cg << 2];
    float4 v0 = *(const float4*)&vbT[e][tg << 3];
    float4 v1 = *(const float4*)&vbT[e][(tg << 3) + 4];
    float va[8] = {v0.x, v0.y, v0.z, v0.w, v1.x, v1.y, v1.z, v1.w};
    float aa[4] = {av.x, av.y, av.z, av.w};
#pragma unroll
    for (int j = 0; j < 8; ++j)
#pragma unroll
      for (int i = 0; i < 4; ++i) acc[j][i] += va[j] * aa[i];
  }
#pragma unroll
  for (int j = 0; j < 8; ++j) {
    int t = t0 + (tg << 3) + j;
    float4 st = make_float4(acc[j][0], acc[j][1], acc[j][2], acc[j][3]);
    *(float4*)&out[(((size_t)((b << 12) + t)) << 9) + (h << 6) + (cg << 2)] = st;
  }
}

// ---------------- fc: f[b,t,n*64+c] = b_fc[n] + sum_m qkvc[b,t,m*64+c]*W_fc[m,n] ----------------
__global__ __launch_bounds__(256) void fc_k(
    const _Float16* __restrict__ qkvc, const float* __restrict__ wfc,
    const float* __restrict__ bfc, _Float16* __restrict__ f) {
  __shared__ float wfcs[216];
  __shared__ float bfcs[9];
  int tid = threadIdx.x;
  if (tid < 216) wfcs[tid] = wfc[tid];
  if (tid < 9) bfcs[tid] = bfc[tid];
  __syncthreads();
  int b = blockIdx.x >> 7;
  int t = ((blockIdx.x & 127) << 5) + (tid >> 3);   // 32 t per block
  int cg = tid & 7;                                  // 8-channel group
  const _Float16* q = qkvc + ((size_t)((b << 12) + t)) * 1536 + (cg << 3);
  float acc[9][8];
#pragma unroll
  for (int n = 0; n < 9; ++n) {
    float bv = bfcs[n];
#pragma unroll
    for (int j = 0; j < 8; ++j) acc[n][j] = bv;
  }
  for (int m = 0; m < 24; ++m) {
    f16x8 v = *(const f16x8*)&q[m << 6];
    float vf[8];
#pragma unroll
    for (int j = 0; j < 8; ++j) vf[j] = (float)v[j];
#pragma unroll
    for (int n = 0; n < 9; ++n) {
      float w = wfcs[m * 9 + n];
#pragma unroll
      for (int j = 0; j < 8; ++j) acc[n][j] += w * vf[j];
    }
  }
  _Float16* fp = f + ((size_t)((b << 12) + t)) * 576 + (cg << 3);
#pragma unroll
  for (int n = 0; n < 9; ++n) {
    f16x8 o;
#pragma unroll
    for (int j = 0; j < 8; ++j) o[j] = (_Float16)acc[n][j];
    *(f16x8*)&fp[n << 6] = o;
  }
}

// ---------------- grouped conv (9in->8out per group, k=3) + ctx chain, += out ----------------
__global__ __launch_bounds__(256) void conv2_k(
    const _Float16* __restrict__ f, const float* __restrict__ x,
    const float* __restrict__ wdep, const float* __restrict__ bdep,
    const float* __restrict__ w1, const float* __restrict__ w2,
    float* __restrict__ out) {
  __shared__ _Float16 fs[34][576];    // f rows t0-1 .. t0+32
  __shared__ _Float16 c1[36][512];    // ctx1 rows tp = t0-2 .. t0+33
  int b = blockIdx.x >> 7;
  int t0 = (blockIdx.x & 127) << 5;   // 32 t per block
  int tid = threadIdx.x;

  // phase A: ctx1 = relu(conv3(x)) for 36 rows (f16 in LDS)
#pragma unroll
  for (int half = 0; half < 2; ++half) {
    int d = (half << 8) + tid;
    float w10 = w1[d * 3], w11 = w1[d * 3 + 1], w12 = w1[d * 3 + 2];
    const float* xb = x + ((size_t)(b << 12)) * 512 + d;
    int tp0 = t0 - 2;
    float xm = (tp0 - 1 >= 0) ? xb[(size_t)(tp0 - 1) * 512] : 0.f;
    float xc = (tp0 >= 0 && tp0 < 4096) ? xb[(size_t)tp0 * 512] : 0.f;
    for (int tl = 0; tl < 36; ++tl) {
      int tp = tp0 + tl;
      float xp = (tp + 1 >= 0 && tp + 1 < 4096) ? xb[(size_t)(tp + 1) * 512] : 0.f;
      float v = 0.f;
      if (tp >= 0 && tp < 4096)
        v = fmaxf(xm * w10 + xc * w11 + xp * w12, 0.f);
      c1[tl][d] = (_Float16)v;
      xm = xc; xc = xp;
    }
  }
  // phase B: stage f rows t0-1 .. t0+32 (vector loads)
  for (int idx = tid; idx < 34 * 72; idx += 256) {
    int row = idx / 72, col = idx - row * 72;
    int t = t0 - 1 + row;
    f16x8 v = {};
    if (t >= 0 && t < 4096)
      v = *(const f16x8*)&f[((size_t)((b << 12) + t)) * 576 + (col << 3)];
    *(f16x8*)&fs[row][col << 3] = v;
  }
  __syncthreads();

  // phase C: per output channel, rolling-register stencil over 32 t
#pragma unroll
  for (int pass = 0; pass < 2; ++pass) {
    int o = (pass << 8) + tid;
    int g9 = (o >> 3) * 9;
    float wd[27];
#pragma unroll
    for (int q = 0; q < 27; ++q) wd[q] = wdep[o * 27 + q];
    float w2r[5];
#pragma unroll
    for (int p = 0; p < 5; ++p) w2r[p] = w2[o * 5 + p];
    float bd = bdep[o];
    float f0[9], f1[9], f2[9];
#pragma unroll
    for (int i = 0; i < 9; ++i) {
      f0[i] = (float)fs[0][g9 + i];
      f1[i] = (float)fs[1][g9 + i];
    }
    float c0 = (float)c1[0][o], cA = (float)c1[1][o], cB = (float)c1[2][o], cC = (float)c1[3][o];
    float* ob = out + ((size_t)((b << 12) + t0)) * 512 + o;
    for (int tl = 0; tl < 32; ++tl) {
      float s = bd;
#pragma unroll
      for (int i = 0; i < 9; ++i) f2[i] = (float)fs[tl + 2][g9 + i];
      float c4 = (float)c1[tl + 4][o];
#pragma unroll
      for (int i = 0; i < 9; ++i)
        s += f0[i] * wd[i * 3 + 0] + f1[i] * wd[i * 3 + 1] + f2[i] * wd[i * 3 + 2];
      s += c0 * w2r[0] + cA * w2r[1] + cB * w2r[2] + cC * w2r[3] + c4 * w2r[4];
      ob[(size_t)tl * 512] += s;
#pragma unroll
      for (int i = 0; i < 9; ++i) { f0[i] = f1[i]; f1[i] = f2[i]; }
      c0 = cA; cA = cB; cB = cC; cC = c4;
    }
  }
}

extern "C" void kernel_launch(void* const* d_in, const int* in_sizes, int n_in,
                              void* d_out, int out_size, void* d_ws, size_t ws_size,
                              hipStream_t stream) {
  (void)in_sizes; (void)n_in; (void)out_size; (void)ws_size;
  const float* x        = (const float*)d_in[0];
  const float* W_qkv    = (const float*)d_in[1];
  const float* w_qkv_dw = (const float*)d_in[2];
  const float* w_ctx1   = (const float*)d_in[3];
  const float* w_ctx2   = (const float*)d_in[4];
  const float* W_fc     = (const float*)d_in[5];
  const float* b_fc     = (const float*)d_in[6];
  const float* w_dep    = (const float*)d_in[7];
  const float* b_dep    = (const float*)d_in[8];
  const float* temperature = (const float*)d_in[9];
  float* out = (float*)d_out;

  // workspace layout (peak ~197 MB):
  //   [0,   96M)   x splits (xhi/xlo/xhis)  -- dead after gemm; qkvc16 overlays
  //   [96M, 99M)   whi/wlos                 -- dead after gemm
  //   [99M, 195M)  qkv16 (f16 32768x1536)   -- dead after dwconv; f overlays
  //   [195M, ...)  Gbuf (1M), attn (1M), norms (48K)
  char* ws = (char*)d_ws;
  _Float16* xhi  = (_Float16*)(ws);
  _Float16* xlo  = (_Float16*)(ws + 33554432);
  _Float16* xhis = (_Float16*)(ws + 67108864);
  _Float16* whi  = (_Float16*)(ws + 100663296);
  _Float16* wlos = (_Float16*)(ws + 102236160);
  _Float16* qkv16  = (_Float16*)(ws + 103809024);
  _Float16* qkvc16 = (_Float16*)(ws);            // overlays x splits (dead)
  _Float16* fbuf   = (_Float16*)(ws + 103809024); // overlays qkv16 (dead after dwconv)
  char* tail = ws + 204472320;
  float* Gbuf  = (float*)(tail);
  float* attn  = (float*)(tail + 1048576);
  float* norms = (float*)(tail + 2097152);

  zero_k<<<1024, 256, 0, stream>>>(Gbuf, norms);
  split_x_k<<<16384, 256, 0, stream>>>(x, xhi, xlo, xhis);
  split_wt_k<<<3072, 256, 0, stream>>>(W_qkv, whi, wlos);
  gemm_qkv_k<<<3072, 256, 0, stream>>>(xhi, xlo, xhis, whi, wlos, qkv16);
  dwconv_k<<<dim3(512, 6), 256, 0, stream>>>(qkv16, w_qkv_dw, qkvc16, norms);
  fc_k<<<1024, 256, 0, stream>>>(qkvc16, W_fc, b_fc, fbuf);
  attn_gram_k<<<dim3(64, 4), 256, 0, stream>>>(qkvc16, Gbuf);
  attn_softmax_k<<<64, 64, 0, stream>>>(Gbuf, norms, temperature, attn);
  attn_out_k<<<2048, 256, 0, stream>>>(qkvc16, attn, out);
  conv2_k<<<1024, 256, 0, stream>>>(fbuf, x, w_dep, b_dep, w_ctx1, w_ctx2, out);
}